// Round 10
// baseline (2245.262 us; speedup 1.0000x reference)
//
#include <hip/hip_runtime.h>
#include <hip/hip_fp16.h>
#include <stdint.h>

#define S_LEN 1024
#define BATCH 64
#define HID   512
#define VOC   256

typedef _Float16 h2v __attribute__((ext_vector_type(2)));
typedef _Float16 h8v __attribute__((ext_vector_type(8)));
typedef float    f4v __attribute__((ext_vector_type(4)));

__device__ __forceinline__ float fdot2f(uint32_t w, uint32_t h, float c) {
#if __has_builtin(__builtin_amdgcn_fdot2)
  return __builtin_amdgcn_fdot2(__builtin_bit_cast(h2v, w),
                                __builtin_bit_cast(h2v, h), c, false);
#else
  h2v a = __builtin_bit_cast(h2v, w);
  h2v b = __builtin_bit_cast(h2v, h);
  return c + (float)a.x * (float)b.x + (float)a.y * (float)b.y;
#endif
}

// ---------------- prep kernels ----------------
__global__ void prep_whh(const float* __restrict__ whh, uint32_t* __restrict__ wp) {
  int idx = blockIdx.x * blockDim.x + threadIdx.x;   // 131072
  int k2 = idx >> 9;
  int n  = idx & 511;
  float a = whh[(2 * k2) * HID + n];
  float b = whh[(2 * k2 + 1) * HID + n];
  h2v p;
  p.x = (_Float16)a;
  p.y = (_Float16)b;
  wp[idx] = __builtin_bit_cast(uint32_t, p);
}

__global__ void prep_why(const float* __restrict__ why, _Float16* __restrict__ wt) {
  int idx = blockIdx.x * blockDim.x + threadIdx.x;   // 131072
  int v = idx >> 9;
  int k = idx & 511;
  wt[idx] = (_Float16)why[k * VOC + v];
}

// 4-col dot expansion for VGPR-held weight words
#define DOT4(W, H)                                         \
  a0 = fdot2f((W).x, (H), a0); a1 = fdot2f((W).y, (H), a1); \
  a2 = fdot2f((W).z, (H), a2); a3 = fdot2f((W).w, (H), a3);

// ---- AGPR weight stash: 1 slice = 4 cols of one k2-pair = 4 AGPRs ----
#define AG_DECL(s) uint32_t ag##s##_0, ag##s##_1, ag##s##_2, ag##s##_3

#define AG_LOAD(s) do {                                                       \
  const uint4 t_ = *((const uint4*)&wp[(size_t)(k2b + (s)) * HID + n0]);      \
  asm volatile("v_accvgpr_write_b32 %0, %1" : "=a"(ag##s##_0) : "v"(t_.x));   \
  asm volatile("v_accvgpr_write_b32 %0, %1" : "=a"(ag##s##_1) : "v"(t_.y));   \
  asm volatile("v_accvgpr_write_b32 %0, %1" : "=a"(ag##s##_2) : "v"(t_.z));   \
  asm volatile("v_accvgpr_write_b32 %0, %1" : "=a"(ag##s##_3) : "v"(t_.w));   \
} while (0)

// volatile fused read+dot: un-hoistable, un-sinkable, minimal live temps
#define AG_DOT1(ACC, AG, H) do { uint32_t t_;                                 \
  asm volatile("v_accvgpr_read_b32 %1, %2\n\tv_dot2_f32_f16 %0, %1, %3, %0"   \
               : "+v"(ACC), "=&v"(t_) : "a"(AG), "v"(H)); } while (0)

#define AG_DOT(s, H) do {            \
  AG_DOT1(a0, ag##s##_0, H);         \
  AG_DOT1(a1, ag##s##_1, H);         \
  AG_DOT1(a2, ag##s##_2, H);         \
  AG_DOT1(a3, ag##s##_3, H); } while (0)

#define AG_QUAD(q, s0, s1, s2, s3) do { const uint4 hc_ = hq[q];              \
  AG_DOT(s0, hc_.x); AG_DOT(s1, hc_.y); AG_DOT(s2, hc_.z); AG_DOT(s3, hc_.w); \
} while (0)

// ---------------- phase 1: recurrence ----------------
// 64 blocks (one chain each), 512 threads = 8 waves, 1 block/CU.
// thread (kq=tid>>7, nb=tid&127): cols n0=nb*4..+3, k2-slices [kq*64, kq*64+64).
// Residency: slices 0..31 AGPR (128 a-regs), 32..47 LDS (128 KB),
//            48..63 streamed from L1 (128 KB/step, two batches of 8).
__global__ __launch_bounds__(512, 2) void rnn_phase1(
    const int* __restrict__ x, const float* __restrict__ wih,
    const uint32_t* __restrict__ wp, const float* __restrict__ bh,
    __half* __restrict__ hbuf) {
  __shared__ __align__(16) uint32_t h2s[HID / 2];  // 1 KB
  __shared__ float part[4][HID];                   // 8 KB
  __shared__ int xtok[S_LEN];                      // 4 KB
  extern __shared__ __align__(16) uint4 lw[];      // 16*512 uint4 = 128 KB

  const int b   = blockIdx.x;
  const int tid = threadIdx.x;
  const int kq  = tid >> 7;
  const int nb  = tid & 127;
  const int n0  = nb * 4;
  const int k2b = kq * 64;

  // ---- AGPR-resident slices 0..31
  AG_DECL(0);  AG_DECL(1);  AG_DECL(2);  AG_DECL(3);
  AG_DECL(4);  AG_DECL(5);  AG_DECL(6);  AG_DECL(7);
  AG_DECL(8);  AG_DECL(9);  AG_DECL(10); AG_DECL(11);
  AG_DECL(12); AG_DECL(13); AG_DECL(14); AG_DECL(15);
  AG_DECL(16); AG_DECL(17); AG_DECL(18); AG_DECL(19);
  AG_DECL(20); AG_DECL(21); AG_DECL(22); AG_DECL(23);
  AG_DECL(24); AG_DECL(25); AG_DECL(26); AG_DECL(27);
  AG_DECL(28); AG_DECL(29); AG_DECL(30); AG_DECL(31);
  AG_LOAD(0);  AG_LOAD(1);  AG_LOAD(2);  AG_LOAD(3);
  AG_LOAD(4);  AG_LOAD(5);  AG_LOAD(6);  AG_LOAD(7);
  AG_LOAD(8);  AG_LOAD(9);  AG_LOAD(10); AG_LOAD(11);
  AG_LOAD(12); AG_LOAD(13); AG_LOAD(14); AG_LOAD(15);
  AG_LOAD(16); AG_LOAD(17); AG_LOAD(18); AG_LOAD(19);
  AG_LOAD(20); AG_LOAD(21); AG_LOAD(22); AG_LOAD(23);
  AG_LOAD(24); AG_LOAD(25); AG_LOAD(26); AG_LOAD(27);
  AG_LOAD(28); AG_LOAD(29); AG_LOAD(30); AG_LOAD(31);

  // ---- LDS-resident slices 32..47 (own weights at lw[si*512+tid])
#pragma unroll
  for (int si = 0; si < 16; ++si)
    lw[si * 512 + tid] = *((const uint4*)&wp[(size_t)(k2b + 32 + si) * HID + n0]);

  xtok[tid]       = x[b * S_LEN + tid];
  xtok[tid + 512] = x[b * S_LEN + tid + 512];
  if (tid < HID / 2) h2s[tid] = 0u;  // h0 = 0
  const float bh_r = bh[tid];
  __syncthreads();

  for (int t = 0; t < S_LEN; ++t) {
    const int tok = xtok[t];
    const float xe = wih[tok * HID + tid];  // early issue; used in reduce

    uint4 g[16];
#pragma unroll
    for (int i = 0; i < 8; ++i)  // stream batch 1 issued early
      g[i] = *((const uint4*)&wp[(size_t)(k2b + 48 + i) * HID + n0]);

    float a0 = 0.f, a1 = 0.f, a2 = 0.f, a3 = 0.f;
    const uint4* hq = (const uint4*)&h2s[k2b];  // wave-uniform broadcast reads

    // AGPR phase: slices 0..31 (quads 0..7)
    AG_QUAD(0,  0,  1,  2,  3);
    AG_QUAD(1,  4,  5,  6,  7);
    AG_QUAD(2,  8,  9, 10, 11);
    AG_QUAD(3, 12, 13, 14, 15);
    AG_QUAD(4, 16, 17, 18, 19);
    AG_QUAD(5, 20, 21, 22, 23);
    AG_QUAD(6, 24, 25, 26, 27);
    AG_QUAD(7, 28, 29, 30, 31);

#pragma unroll
    for (int i = 8; i < 16; ++i)  // stream batch 2 issued under LDS phase
      g[i] = *((const uint4*)&wp[(size_t)(k2b + 48 + i) * HID + n0]);

    // LDS phase: slices 32..47 (quads 8..11)
#pragma unroll
    for (int q = 0; q < 4; ++q) {
      const uint4 hc = hq[8 + q];
      const uint4 l0 = lw[(q * 4 + 0) * 512 + tid];
      const uint4 l1 = lw[(q * 4 + 1) * 512 + tid];
      const uint4 l2 = lw[(q * 4 + 2) * 512 + tid];
      const uint4 l3 = lw[(q * 4 + 3) * 512 + tid];
      DOT4(l0, hc.x)
      DOT4(l1, hc.y)
      DOT4(l2, hc.z)
      DOT4(l3, hc.w)
    }

    // stream phase: slices 48..63 (quads 12..15)
#pragma unroll
    for (int q = 0; q < 4; ++q) {
      const uint4 hc = hq[12 + q];
      DOT4(g[q * 4 + 0], hc.x)
      DOT4(g[q * 4 + 1], hc.y)
      DOT4(g[q * 4 + 2], hc.z)
      DOT4(g[q * 4 + 3], hc.w)
    }

    *((float4*)&part[kq][n0]) = make_float4(a0, a1, a2, a3);
    __syncthreads();  // B1: partials ready; all h2s reads of step t done

    {
      float s = part[0][tid] + part[1][tid] + part[2][tid] + part[3][tid];
      s += xe + bh_r;
      const float e = __builtin_amdgcn_exp2f(s * 2.885390081777927f);  // e^(2s)
      const float h = 1.0f - 2.0f * __builtin_amdgcn_rcpf(e + 1.0f);
      const __half hh = __float2half(h);
      hbuf[(size_t)(t * BATCH + b) * HID + tid] = hh;  // history for phase 2
      ((__half*)h2s)[tid] = hh;                         // recurrent state
    }
    __syncthreads();  // B2: new h visible before next step's reads
  }
}

// ---------------- phase 2: y = h @ W_hy + b_y (fp16 MFMA, in-place over d_out) ----
__global__ __launch_bounds__(256, 1) void rnn_phase2(
    void* __restrict__ out_, const _Float16* __restrict__ wt,
    const float* __restrict__ by) {
  const int tid = threadIdx.x;
  const int w = tid >> 6;
  const int l = tid & 63;
  const int la = l & 15;
  const int lb = l >> 4;
  const int rowbase = blockIdx.x * 64 + w * 16;

  const _Float16* hb = (const _Float16*)out_;
  float* out = (float*)out_;

  h8v a[16];
  const _Float16* arow = hb + (size_t)(rowbase + la) * HID + lb * 8;
#pragma unroll
  for (int kk = 0; kk < 16; ++kk)
    a[kk] = *((const h8v*)(arow + kk * 32));

#pragma unroll 1
  for (int cb = 0; cb < 16; ++cb) {
    f4v acc = {0.f, 0.f, 0.f, 0.f};
    const _Float16* brow = wt + (size_t)(cb * 16 + la) * HID + lb * 8;
#pragma unroll
    for (int kk = 0; kk < 16; ++kk) {
      const h8v bf = *((const h8v*)(brow + kk * 32));
      acc = __builtin_amdgcn_mfma_f32_16x16x32_f16(a[kk], bf, acc, 0, 0, 0);
    }
    const int col = cb * 16 + la;
    const float byv = by[col];
#pragma unroll
    for (int r = 0; r < 4; ++r) {
      const int row = rowbase + lb * 4 + r;  // C/D: col = lane&15, row = (lane>>4)*4 + r
      out[(size_t)row * VOC + col] = acc[r] + byv;
    }
  }
}

// ---------------- launch ----------------
extern "C" void kernel_launch(void* const* d_in, const int* in_sizes, int n_in,
                              void* d_out, int out_size, void* d_ws, size_t ws_size,
                              hipStream_t stream) {
  const int*   x   = (const int*)d_in[0];
  const float* wih = (const float*)d_in[1];
  const float* whh = (const float*)d_in[2];
  const float* bh  = (const float*)d_in[3];
  const float* why = (const float*)d_in[4];
  const float* by  = (const float*)d_in[5];

  uint32_t* wp = (uint32_t*)d_ws;                          // 512 KB packed fp16 W_hh
  _Float16* wt = (_Float16*)((char*)d_ws + 512 * 1024);    // 256 KB fp16 W_hy^T

  hipLaunchKernelGGL(prep_whh, dim3(512), dim3(256), 0, stream, whh, wp);
  hipLaunchKernelGGL(prep_why, dim3(512), dim3(256), 0, stream, why, wt);
  hipLaunchKernelGGL(rnn_phase1, dim3(BATCH), dim3(512), 131072, stream,
                     x, wih, wp, bh, (__half*)d_out);
  hipLaunchKernelGGL(rnn_phase2, dim3((S_LEN * BATCH) / 64), dim3(256), 0, stream,
                     d_out, wt, by);
}